// Round 3
// baseline (745.234 us; speedup 1.0000x reference)
//
#include <hip/hip_runtime.h>

#define Bv 4
#define Lv 1024
#define Ev 256
#define Hv 8
#define DHv 32
#define CH 128   // attention score-chunk (fallback loop; typical cnt~51 fits once)

// ---------------------------------------------------------------------------
// GEMM: C[r0:r0+64, c0:c0+64] = A @ W^T + bias, for one of up to 3 weight sets.
// blockIdx.x = row tile (4096/64 = 64); blockIdx.y = g*4 + coltile.
// 256 threads, 4x4 micro-tile. LDS tiles transposed [k][r], pad 68 keeps
// 16B alignment for ds_read_b128 (4-way conflict on staging writes only —
// write cost is ~10% of compute, acceptable).
// ---------------------------------------------------------------------------
__global__ __launch_bounds__(256) void gemm_fused(
    const float* __restrict__ A,
    const float* __restrict__ W0, const float* __restrict__ b0, float* __restrict__ C0,
    const float* __restrict__ W1, const float* __restrict__ b1, float* __restrict__ C1,
    const float* __restrict__ W2, const float* __restrict__ b2, float* __restrict__ C2) {
    __shared__ float Xs[32][68];
    __shared__ float Ws[32][68];
    const int g = blockIdx.y >> 2;
    const float* __restrict__ W    = (g == 0) ? W0 : (g == 1) ? W1 : W2;
    const float* __restrict__ bias = (g == 0) ? b0 : (g == 1) ? b1 : b2;
    float* __restrict__ C          = (g == 0) ? C0 : (g == 1) ? C1 : C2;

    const int row0 = blockIdx.x * 64;
    const int col0 = (blockIdx.y & 3) * 64;
    const int t = threadIdx.x;
    const int tx = t & 15, ty = t >> 4;
    const int lr = t >> 2;            // 0..63: tile row
    const int lk = (t & 3) * 8;       // 0,8,16,24: k-offset of this thread's 8 floats

    float acc[4][4] = {};

    for (int k0 = 0; k0 < 256; k0 += 32) {
        const float4 a0 = *(const float4*)&A[(size_t)(row0 + lr) * 256 + k0 + lk];
        const float4 a1 = *(const float4*)&A[(size_t)(row0 + lr) * 256 + k0 + lk + 4];
        const float4 w0 = *(const float4*)&W[(size_t)(col0 + lr) * 256 + k0 + lk];
        const float4 w1 = *(const float4*)&W[(size_t)(col0 + lr) * 256 + k0 + lk + 4];
        Xs[lk + 0][lr] = a0.x; Xs[lk + 1][lr] = a0.y; Xs[lk + 2][lr] = a0.z; Xs[lk + 3][lr] = a0.w;
        Xs[lk + 4][lr] = a1.x; Xs[lk + 5][lr] = a1.y; Xs[lk + 6][lr] = a1.z; Xs[lk + 7][lr] = a1.w;
        Ws[lk + 0][lr] = w0.x; Ws[lk + 1][lr] = w0.y; Ws[lk + 2][lr] = w0.z; Ws[lk + 3][lr] = w0.w;
        Ws[lk + 4][lr] = w1.x; Ws[lk + 5][lr] = w1.y; Ws[lk + 6][lr] = w1.z; Ws[lk + 7][lr] = w1.w;
        __syncthreads();

        #pragma unroll
        for (int kk = 0; kk < 32; ++kk) {
            const float4 a4 = *(const float4*)&Xs[kk][ty * 4];
            const float4 b4 = *(const float4*)&Ws[kk][tx * 4];
            const float aa[4] = {a4.x, a4.y, a4.z, a4.w};
            const float bb[4] = {b4.x, b4.y, b4.z, b4.w};
            #pragma unroll
            for (int ri = 0; ri < 4; ++ri)
                #pragma unroll
                for (int ci = 0; ci < 4; ++ci)
                    acc[ri][ci] = fmaf(aa[ri], bb[ci], acc[ri][ci]);
        }
        __syncthreads();
    }

    const float4 bv4 = *(const float4*)&bias[col0 + tx * 4];
    #pragma unroll
    for (int ri = 0; ri < 4; ++ri) {
        const int row = row0 + ty * 4 + ri;
        float4 o;
        o.x = acc[ri][0] + bv4.x; o.y = acc[ri][1] + bv4.y;
        o.z = acc[ri][2] + bv4.z; o.w = acc[ri][3] + bv4.w;
        *(float4*)&C[(size_t)row * 256 + col0 + tx * 4] = o;
    }
}

// ---------------------------------------------------------------------------
// Sparse attention: one block per (b, n), 256 threads.
// Phase 1: compact ALL active m's of the row into idxm (ballot + LDS atomic).
// Phase 2: (normally once, chunked at 128 for arbitrary density) scores for
//          (entry, head) tasks -> softmax (online merge) -> PV accumulate.
// ---------------------------------------------------------------------------
__global__ __launch_bounds__(256) void attn_sparse(const float* __restrict__ Qb,
                                                   const float* __restrict__ Kb,
                                                   const float* __restrict__ Vb,
                                                   const int* __restrict__ adj,
                                                   const float* __restrict__ KE,
                                                   float* __restrict__ AT) {
    __shared__ __align__(16) float Qs[Ev];
    __shared__ int idxm[Lv];                    // 4 KB: all active m's of the row
    __shared__ __align__(16) float S[Hv][CH + 4];
    __shared__ int cntS;
    __shared__ float mh[Hv], lh[Hv], scaleh[Hv];

    const int bid = blockIdx.x;
    const int b = bid >> 10;
    const int n = bid & 1023;
    const int t = threadIdx.x;
    const int lane = t & 63;
    const int h8 = t >> 5;                      // output head for element e = t
    const size_t nrow = (size_t)(b * Lv + n) * Lv;

    Qs[t] = Qb[(size_t)(b * Lv + n) * Ev + t] * 0.0625f;   // 1/sqrt(256)
    if (t == 0) cntS = 0;
    if (t < Hv) { mh[t] = -1e30f; lh[t] = 0.f; }
    __syncthreads();

    // --- phase 1: compact the whole row (4 rounds x 256 columns) ---
    #pragma unroll
    for (int c = 0; c < 4; ++c) {
        const int m = c * 256 + t;
        const bool p = adj[nrow + m] != 0;
        const unsigned long long mask = __ballot(p);
        const int prefix = __popcll(mask & ((1ull << lane) - 1ull));
        int base = 0;
        if (lane == 0) base = atomicAdd(&cntS, (int)__popcll(mask));
        base = __shfl(base, 0, 64);
        if (p) idxm[base + prefix] = m;
    }
    __syncthreads();

    const int cnt = cntS;
    float acc = 0.f;
    const float* __restrict__ vcol = Vb + (size_t)b * Lv * Ev + t;
    const float4* __restrict__ K4 = (const float4*)Kb;
    const float4* __restrict__ KE4 = (const float4*)KE;
    const float4* __restrict__ Q4 = (const float4*)Qs;

    // --- phase 2: normally a single iteration (cnt ~ 51 << CH) ---
    for (int eb = 0; eb < cnt; eb += CH) {
        const int cc = min(CH, cnt - eb);

        // scores for (entry, head) tasks
        for (int task = t; task < cc * 8; task += 256) {
            const int ei = task >> 3, h = task & 7;
            const int mm = idxm[eb + ei];
            const float4* kp = K4 + (size_t)(b * Lv + mm) * 64 + h * 8;
            const float4* kep = KE4 + (nrow + mm) * 8;
            const float4* qp = Q4 + h * 8;
            float dot = 0.f;
            #pragma unroll
            for (int j = 0; j < 8; ++j) {
                const float4 kv = kp[j], kf = kep[j], qv = qp[j];
                dot = fmaf(qv.x, kv.x + kf.x, dot);
                dot = fmaf(qv.y, kv.y + kf.y, dot);
                dot = fmaf(qv.z, kv.z + kf.z, dot);
                dot = fmaf(qv.w, kv.w + kf.w, dot);
            }
            S[h][ei] = dot;
        }
        __syncthreads();

        // online softmax merge: 32 threads per head
        {
            const int h = t >> 5, d = t & 31;
            float cmax = -1e30f;
            for (int i = d; i < cc; i += 32) cmax = fmaxf(cmax, S[h][i]);
            #pragma unroll
            for (int off = 16; off >= 1; off >>= 1)
                cmax = fmaxf(cmax, __shfl_xor(cmax, off, 64));
            const float oldm = mh[h];
            const float newm = fmaxf(oldm, cmax);
            float csum = 0.f;
            for (int i = d; i < cc; i += 32) {
                const float pz = __expf(S[h][i] - newm);
                S[h][i] = pz;
                csum += pz;
            }
            #pragma unroll
            for (int off = 16; off >= 1; off >>= 1)
                csum += __shfl_xor(csum, off, 64);
            if (d == 0) {
                const float sc = __expf(oldm - newm);
                scaleh[h] = sc;
                lh[h] = lh[h] * sc + csum;
                mh[h] = newm;
            }
        }
        __syncthreads();

        // PV accumulate: thread t owns output element e = t
        acc *= scaleh[h8];
        {
            int i = 0;
            for (; i + 4 <= cc; i += 4) {
                const int m0 = idxm[eb + i],     m1 = idxm[eb + i + 1];
                const int m2 = idxm[eb + i + 2], m3 = idxm[eb + i + 3];
                const float p0 = S[h8][i],     p1 = S[h8][i + 1];
                const float p2 = S[h8][i + 2], p3 = S[h8][i + 3];
                const float v0 = vcol[(size_t)m0 * Ev];
                const float v1 = vcol[(size_t)m1 * Ev];
                const float v2 = vcol[(size_t)m2 * Ev];
                const float v3 = vcol[(size_t)m3 * Ev];
                acc = fmaf(p0, v0, acc);
                acc = fmaf(p1, v1, acc);
                acc = fmaf(p2, v2, acc);
                acc = fmaf(p3, v3, acc);
            }
            for (; i < cc; ++i)
                acc = fmaf(S[h8][i], vcol[(size_t)idxm[eb + i] * Ev], acc);
        }
        __syncthreads();
    }

    AT[(size_t)(b * Lv + n) * Ev + t] = acc / lh[h8];
}

// ---------------------------------------------------------------------------
extern "C" void kernel_launch(void* const* d_in, const int* in_sizes, int n_in,
                              void* d_out, int out_size, void* d_ws, size_t ws_size,
                              hipStream_t stream) {
    const float* X   = (const float*)d_in[0];
    const int*   adj = (const int*)d_in[1];
    const float* KE  = (const float*)d_in[2];
    const float* Wq  = (const float*)d_in[3];
    const float* bq  = (const float*)d_in[4];
    const float* Wk  = (const float*)d_in[5];
    const float* bk  = (const float*)d_in[6];
    const float* Wv  = (const float*)d_in[7];
    const float* bv  = (const float*)d_in[8];
    const float* Wo  = (const float*)d_in[9];
    const float* bo  = (const float*)d_in[10];

    const size_t NE = (size_t)Bv * Lv * Ev;   // 1M floats = 4MB
    float* Qb = (float*)d_ws;
    float* Kb = Qb + NE;
    float* Vb = Kb + NE;
    float* AT = Vb + NE;
    float* out = (float*)d_out;

    const dim3 blk(256);

    // fused Q/K/V projections: 64 row-tiles x (3 mats x 4 col-tiles) = 768 blocks
    hipLaunchKernelGGL(gemm_fused, dim3(64, 12), blk, 0, stream, X,
                       Wq, bq, Qb, Wk, bk, Kb, Wv, bv, Vb);
    hipLaunchKernelGGL(attn_sparse, dim3(Bv * Lv), blk, 0, stream,
                       Qb, Kb, Vb, adj, KE, AT);
    // output projection (g is always 0)
    hipLaunchKernelGGL(gemm_fused, dim3(64, 4), blk, 0, stream, AT,
                       Wo, bo, out, Wo, bo, out, Wo, bo, out);
}